// Round 2
// baseline (661.266 us; speedup 1.0000x reference)
//
#include <hip/hip_runtime.h>

#define HID 512
#define NH 8
#define HD 64
#define BATCH 4
#define SEQ 2048
#define MTOT (BATCH * SEQ)   // 8192

typedef unsigned short ushort_t;
typedef __bf16 bf16x8 __attribute__((ext_vector_type(8)));
typedef unsigned short ushort8v __attribute__((ext_vector_type(8)));
typedef float floatx4 __attribute__((ext_vector_type(4)));

static __device__ __forceinline__ unsigned short f2bf(float f) {
  union { float f; unsigned int u; } c; c.f = f;
  unsigned int u = c.u;
  u += 0x7fff + ((u >> 16) & 1);   // round-to-nearest-even
  return (unsigned short)(u >> 16);
}
static __device__ __forceinline__ float bf2f(unsigned short s) {
  union { unsigned int u; float f; } c; c.u = ((unsigned int)s) << 16;
  return c.f;
}
static __device__ __forceinline__ bf16x8 asbf(ushort8v v) {
  return __builtin_bit_cast(bf16x8, v);
}

// ---------- dtype detector: bf16-packed vs fp32, voting on low-half exponent ----------
__global__ void detect_dtype(const unsigned int* __restrict__ q, int* __restrict__ flag) {
  if (threadIdx.x == 0 && blockIdx.x == 0) {
    int hits = 0;
    for (int i = 0; i < 256; ++i) {
      unsigned e = (q[i] >> 7) & 0xff;          // exponent field of LOW bf16 half
      hits += (e >= 110 && e <= 136) ? 1 : 0;   // N(0,1) bf16 lands here ~always
    }
    flag[0] = (hits >= 128) ? 1 : 0;            // 1 = bf16 inputs, 0 = fp32 inputs
  }
}

// ---------- weight transpose+convert: T[n][k] = bf16(W[k][n]) ----------
__global__ __launch_bounds__(256) void prep_w(
    const void* __restrict__ W0, const void* __restrict__ W1,
    const void* __restrict__ W2, const void* __restrict__ W3,
    ushort_t* __restrict__ T0, ushort_t* __restrict__ T1,
    ushort_t* __restrict__ T2, ushort_t* __restrict__ T3,
    const int* __restrict__ flag) {
  const int isbf = flag[0];
  const void* W; ushort_t* T;
  switch (blockIdx.y) {
    case 0: W = W0; T = T0; break;
    case 1: W = W1; T = T1; break;
    case 2: W = W2; T = T2; break;
    default: W = W3; T = T3; break;
  }
  int idx = blockIdx.x * 256 + threadIdx.x;   // 0 .. 512*512-1
  int k = idx >> 9, n = idx & 511;
  ushort_t v = isbf ? ((const ushort_t*)W)[k * HID + n]
                    : f2bf(((const float*)W)[k * HID + n]);
  T[n * HID + k] = v;
}

// ---------- bias convert: biasF[t][j] = float(b_t[j]) ----------
__global__ __launch_bounds__(256) void prep_b(
    const void* __restrict__ B0, const void* __restrict__ B1,
    const void* __restrict__ B2, const void* __restrict__ B3,
    float* __restrict__ biasF, const int* __restrict__ flag) {
  const int isbf = flag[0];
  int i = blockIdx.x * 256 + threadIdx.x;     // 0..2047
  int t = i >> 9, j = i & 511;
  const void* B = (t == 0) ? B0 : (t == 1) ? B1 : (t == 2) ? B2 : B3;
  biasF[i] = isbf ? bf2f(((const ushort_t*)B)[j]) : ((const float*)B)[j];
}

// ---------- GEMM (input proj): Y_bf16[M,512] = X @ Wt^T + bias ----------
__global__ __launch_bounds__(256) void gemm_in(
    const void* __restrict__ X, const ushort_t* __restrict__ Wt,
    const float* __restrict__ biasF, ushort_t* __restrict__ Y,
    const int* __restrict__ flag) {
  const int isbf = flag[0];
  int wave = (blockIdx.x << 2) + (threadIdx.x >> 6);
  int lane = threadIdx.x & 63;
  int id = lane & 15, quad = lane >> 4;
  int tn = wave & 31, tm = wave >> 5;
  long arow = (long)(tm * 16 + id) * HID + quad * 8;
  const ushort_t* bp = Wt + (tn * 16 + id) * HID + quad * 8;
  floatx4 acc = {0.f, 0.f, 0.f, 0.f};
  if (isbf) {
    const ushort_t* ap = (const ushort_t*)X + arow;
#pragma unroll
    for (int k0 = 0; k0 < HID; k0 += 32) {
      ushort8v a = *(const ushort8v*)(ap + k0);
      ushort8v b = *(const ushort8v*)(bp + k0);
      acc = __builtin_amdgcn_mfma_f32_16x16x32_bf16(asbf(a), asbf(b), acc, 0, 0, 0);
    }
  } else {
    const float* apf = (const float*)X + arow;
#pragma unroll
    for (int k0 = 0; k0 < HID; k0 += 32) {
      floatx4 f0 = *(const floatx4*)(apf + k0);
      floatx4 f1 = *(const floatx4*)(apf + k0 + 4);
      ushort8v a;
#pragma unroll
      for (int i = 0; i < 4; ++i) { a[i] = f2bf(f0[i]); a[4 + i] = f2bf(f1[i]); }
      ushort8v b = *(const ushort8v*)(bp + k0);
      acc = __builtin_amdgcn_mfma_f32_16x16x32_bf16(asbf(a), asbf(b), acc, 0, 0, 0);
    }
  }
  float bv = biasF[tn * 16 + id];
  int row0 = tm * 16 + quad * 4;
  int col  = tn * 16 + id;
#pragma unroll
  for (int r = 0; r < 4; ++r)
    Y[(row0 + r) * HID + col] = f2bf(acc[r] + bv);
}

// ---------- GEMM (output proj): out = Cp @ WoT^T + bo, store per flag ----------
__global__ __launch_bounds__(256) void gemm_out(
    const ushort_t* __restrict__ X, const ushort_t* __restrict__ Wt,
    const float* __restrict__ biasF, void* __restrict__ out,
    const int* __restrict__ flag) {
  const int isbf = flag[0];
  int wave = (blockIdx.x << 2) + (threadIdx.x >> 6);
  int lane = threadIdx.x & 63;
  int id = lane & 15, quad = lane >> 4;
  int tn = wave & 31, tm = wave >> 5;
  const ushort_t* ap = X  + (long)(tm * 16 + id) * HID + quad * 8;
  const ushort_t* bp = Wt + (tn * 16 + id) * HID + quad * 8;
  floatx4 acc = {0.f, 0.f, 0.f, 0.f};
#pragma unroll
  for (int k0 = 0; k0 < HID; k0 += 32) {
    ushort8v a = *(const ushort8v*)(ap + k0);
    ushort8v b = *(const ushort8v*)(bp + k0);
    acc = __builtin_amdgcn_mfma_f32_16x16x32_bf16(asbf(a), asbf(b), acc, 0, 0, 0);
  }
  float bv = biasF[tn * 16 + id];
  int row0 = tm * 16 + quad * 4;
  int col  = tn * 16 + id;
  if (isbf) {
    ushort_t* o = (ushort_t*)out;
#pragma unroll
    for (int r = 0; r < 4; ++r) o[(row0 + r) * HID + col] = f2bf(acc[r] + bv);
  } else {
    float* o = (float*)out;
#pragma unroll
    for (int r = 0; r < 4; ++r) o[(row0 + r) * HID + col] = acc[r] + bv;
  }
}

// ---------- flash attention (all-bf16 ws tensors) ----------
__global__ __launch_bounds__(256) void flash_attn(
    const ushort_t* __restrict__ Q, const ushort_t* __restrict__ K,
    const ushort_t* __restrict__ V, const int* __restrict__ mask,
    ushort_t* __restrict__ ctx) {
  int qb = blockIdx.x, h = blockIdx.y, b = blockIdx.z;
  int tid = threadIdx.x;
  int wid = tid >> 6, lane = tid & 63;
  int id = lane & 15, quad = lane >> 4;

  __shared__ ushort_t Kt[32 * 64];       // [k][d]
  __shared__ ushort_t Vt[64 * 32];       // [d][k]
  __shared__ ushort_t Pl[4][16 * 32];    // per-wave P tile [q][k]

  const ushort_t* Qb = Q + (long)(b * SEQ + qb * 64 + wid * 16) * HID + h * HD;
  const ushort_t* Kb = K + (long)(b * SEQ) * HID + h * HD;
  const ushort_t* Vb = V + (long)(b * SEQ) * HID + h * HD;
  const int* mrow = mask + b * SEQ;

  ushort8v q0 = *(const ushort8v*)(Qb + id * HID + quad * 8);
  ushort8v q1 = *(const ushort8v*)(Qb + id * HID + 32 + quad * 8);

  floatx4 o[4];
  float m_i[4], l_i[4];
#pragma unroll
  for (int dg = 0; dg < 4; ++dg) o[dg] = (floatx4){0.f, 0.f, 0.f, 0.f};
#pragma unroll
  for (int r = 0; r < 4; ++r) { m_i[r] = -1e30f; l_i[r] = 0.f; }

  int sr = tid >> 3;            // 0..31
  int sc = (tid & 7) * 8;       // 0..56

  for (int kb = 0; kb < SEQ / 32; ++kb) {
    {
      ushort8v kv = *(const ushort8v*)(Kb + (long)(kb * 32 + sr) * HID + sc);
      *(ushort8v*)(&Kt[sr * 64 + sc]) = kv;
      ushort8v vv = *(const ushort8v*)(Vb + (long)(kb * 32 + sr) * HID + sc);
#pragma unroll
      for (int i = 0; i < 8; ++i) Vt[(sc + i) * 32 + sr] = vv[i];
    }
    __syncthreads();

    floatx4 s[2];
#pragma unroll
    for (int st = 0; st < 2; ++st) {
      ushort8v k0 = *(const ushort8v*)(&Kt[(st * 16 + id) * 64 + quad * 8]);
      ushort8v k1 = *(const ushort8v*)(&Kt[(st * 16 + id) * 64 + 32 + quad * 8]);
      floatx4 acc = {0.f, 0.f, 0.f, 0.f};
      acc = __builtin_amdgcn_mfma_f32_16x16x32_bf16(asbf(q0), asbf(k0), acc, 0, 0, 0);
      acc = __builtin_amdgcn_mfma_f32_16x16x32_bf16(asbf(q1), asbf(k1), acc, 0, 0, 0);
      s[st] = acc;
    }
    int ok0 = mrow[kb * 32 + id];
    int ok1 = mrow[kb * 32 + 16 + id];
#pragma unroll
    for (int r = 0; r < 4; ++r) {
      s[0][r] = ok0 ? s[0][r] * 0.125f : -1e9f;
      s[1][r] = ok1 ? s[1][r] * 0.125f : -1e9f;
    }

#pragma unroll
    for (int r = 0; r < 4; ++r) {
      float mx = fmaxf(s[0][r], s[1][r]);
      mx = fmaxf(mx, __shfl_xor(mx, 1));
      mx = fmaxf(mx, __shfl_xor(mx, 2));
      mx = fmaxf(mx, __shfl_xor(mx, 4));
      mx = fmaxf(mx, __shfl_xor(mx, 8));
      float mnew = fmaxf(m_i[r], mx);
      float alpha = __expf(m_i[r] - mnew);
      float p0 = __expf(s[0][r] - mnew);
      float p1 = __expf(s[1][r] - mnew);
      float rs = p0 + p1;
      rs += __shfl_xor(rs, 1);
      rs += __shfl_xor(rs, 2);
      rs += __shfl_xor(rs, 4);
      rs += __shfl_xor(rs, 8);
      l_i[r] = l_i[r] * alpha + rs;
      m_i[r] = mnew;
#pragma unroll
      for (int dg = 0; dg < 4; ++dg) o[dg][r] *= alpha;
      Pl[wid][(quad * 4 + r) * 32 + id]      = f2bf(p0);
      Pl[wid][(quad * 4 + r) * 32 + 16 + id] = f2bf(p1);
    }
    __syncthreads();

    ushort8v pf = *(const ushort8v*)(&Pl[wid][id * 32 + quad * 8]);
#pragma unroll
    for (int dg = 0; dg < 4; ++dg) {
      ushort8v vf = *(const ushort8v*)(&Vt[(dg * 16 + id) * 32 + quad * 8]);
      o[dg] = __builtin_amdgcn_mfma_f32_16x16x32_bf16(asbf(pf), asbf(vf), o[dg], 0, 0, 0);
    }
    __syncthreads();
  }

  int qrow = qb * 64 + wid * 16 + quad * 4;
#pragma unroll
  for (int r = 0; r < 4; ++r) {
    float inv = 1.0f / l_i[r];
#pragma unroll
    for (int dg = 0; dg < 4; ++dg) {
      ctx[(long)(b * SEQ + qrow + r) * HID + h * HD + dg * 16 + id] = f2bf(o[dg][r] * inv);
    }
  }
}

extern "C" void kernel_launch(void* const* d_in, const int* in_sizes, int n_in,
                              void* d_out, int out_size, void* d_ws, size_t ws_size,
                              hipStream_t stream) {
  const void* values = d_in[0];
  const void* keys   = d_in[1];
  const void* query  = d_in[2];
  const int*  mask   = (const int*)d_in[3];
  const void* Wq = d_in[4];  const void* bq = d_in[5];
  const void* Wk = d_in[6];  const void* bk = d_in[7];
  const void* Wv = d_in[8];  const void* bv = d_in[9];
  const void* Wo = d_in[10]; const void* bo = d_in[11];

  // ws layout
  ushort_t* ws = (ushort_t*)d_ws;
  const size_t NEL = (size_t)MTOT * HID;       // 4,194,304
  ushort_t* Qp  = ws;
  ushort_t* Kp  = ws + NEL;
  ushort_t* Vp  = ws + 2 * NEL;
  ushort_t* Cp  = ws + 3 * NEL;
  ushort_t* WqT = ws + 4 * NEL;
  ushort_t* WkT = WqT + (size_t)HID * HID;
  ushort_t* WvT = WkT + (size_t)HID * HID;
  ushort_t* WoT = WvT + (size_t)HID * HID;
  float* biasF  = (float*)(WoT + (size_t)HID * HID);   // 4*512 floats
  int* flag     = (int*)(biasF + 4 * HID);

  detect_dtype<<<1, 64, 0, stream>>>((const unsigned int*)query, flag);
  prep_w<<<dim3(1024, 4), 256, 0, stream>>>(Wq, Wk, Wv, Wo, WqT, WkT, WvT, WoT, flag);
  prep_b<<<8, 256, 0, stream>>>(bq, bk, bv, bo, biasF, flag);

  const int gemm_blocks = (MTOT / 16) * (HID / 16) / 4;  // 4096
  gemm_in<<<gemm_blocks, 256, 0, stream>>>(query,  WqT, biasF + 0 * HID, Qp, flag);
  gemm_in<<<gemm_blocks, 256, 0, stream>>>(keys,   WkT, biasF + 1 * HID, Kp, flag);
  gemm_in<<<gemm_blocks, 256, 0, stream>>>(values, WvT, biasF + 2 * HID, Vp, flag);

  flash_attn<<<dim3(SEQ / 64, NH, BATCH), 256, 0, stream>>>(Qp, Kp, Vp, mask, Cp);

  gemm_out<<<gemm_blocks, 256, 0, stream>>>(Cp, WoT, biasF + 3 * HID, d_out, flag);
}

// Round 6
// 527.485 us; speedup vs baseline: 1.2536x; 1.2536x over previous
//
#include <hip/hip_runtime.h>

#define HID 512
#define NH 8
#define HD 64
#define BATCH 4
#define SEQ 2048
#define MTOT (BATCH * SEQ)   // 8192

typedef unsigned short ushort_t;
typedef __bf16 bf16x8 __attribute__((ext_vector_type(8)));
typedef unsigned short ushort8v __attribute__((ext_vector_type(8)));
typedef unsigned short ushort4v __attribute__((ext_vector_type(4)));
typedef float floatx4 __attribute__((ext_vector_type(4)));
typedef int intx4 __attribute__((ext_vector_type(4)));

static __device__ __forceinline__ unsigned short f2bf(float f) {
  union { float f; unsigned int u; } c; c.f = f;
  unsigned int u = c.u;
  u += 0x7fff + ((u >> 16) & 1);   // RNE
  return (unsigned short)(u >> 16);
}
static __device__ __forceinline__ float bf2f(unsigned short s) {
  union { unsigned int u; float f; } c; c.u = ((unsigned int)s) << 16;
  return c.f;
}
static __device__ __forceinline__ bf16x8 asbf(ushort8v v) {
  return __builtin_bit_cast(bf16x8, v);
}

// ---------- dtype detector (round-2 proven) ----------
__global__ void detect_dtype(const unsigned int* __restrict__ q, int* __restrict__ flag) {
  if (threadIdx.x == 0 && blockIdx.x == 0) {
    int hits = 0;
    for (int i = 0; i < 256; ++i) {
      unsigned e = (q[i] >> 7) & 0xff;
      hits += (e >= 110 && e <= 136) ? 1 : 0;
    }
    flag[0] = (hits >= 128) ? 1 : 0;
  }
}

// ---------- weight transpose+convert (round-2 proven) ----------
__global__ __launch_bounds__(256) void prep_w(
    const void* __restrict__ W0, const void* __restrict__ W1,
    const void* __restrict__ W2, const void* __restrict__ W3,
    ushort_t* __restrict__ T0, ushort_t* __restrict__ T1,
    ushort_t* __restrict__ T2, ushort_t* __restrict__ T3,
    const int* __restrict__ flag) {
  const int isbf = flag[0];
  const void* W; ushort_t* T;
  switch (blockIdx.y) {
    case 0: W = W0; T = T0; break;
    case 1: W = W1; T = T1; break;
    case 2: W = W2; T = T2; break;
    default: W = W3; T = T3; break;
  }
  int idx = blockIdx.x * 256 + threadIdx.x;
  int k = idx >> 9, n = idx & 511;
  ushort_t v = isbf ? ((const ushort_t*)W)[k * HID + n]
                    : f2bf(((const float*)W)[k * HID + n]);
  T[n * HID + k] = v;
}

// ---------- bias convert (round-2 proven) ----------
__global__ __launch_bounds__(256) void prep_b(
    const void* __restrict__ B0, const void* __restrict__ B1,
    const void* __restrict__ B2, const void* __restrict__ B3,
    float* __restrict__ biasF, const int* __restrict__ flag) {
  const int isbf = flag[0];
  int i = blockIdx.x * 256 + threadIdx.x;
  int t = i >> 9, j = i & 511;
  const void* B = (t == 0) ? B0 : (t == 1) ? B1 : (t == 2) ? B2 : B3;
  biasF[i] = isbf ? bf2f(((const ushort_t*)B)[j]) : ((const float*)B)[j];
}

// ---------- GEMM input proj (round-2 proven) ----------
__global__ __launch_bounds__(256) void gemm_in(
    const void* __restrict__ X, const ushort_t* __restrict__ Wt,
    const float* __restrict__ biasF, ushort_t* __restrict__ Y,
    const int* __restrict__ flag) {
  const int isbf = flag[0];
  int wave = (blockIdx.x << 2) + (threadIdx.x >> 6);
  int lane = threadIdx.x & 63;
  int id = lane & 15, quad = lane >> 4;
  int tn = wave & 31, tm = wave >> 5;
  long arow = (long)(tm * 16 + id) * HID + quad * 8;
  const ushort_t* bp = Wt + (tn * 16 + id) * HID + quad * 8;
  floatx4 acc = {0.f, 0.f, 0.f, 0.f};
  if (isbf) {
    const ushort_t* ap = (const ushort_t*)X + arow;
#pragma unroll
    for (int k0 = 0; k0 < HID; k0 += 32) {
      ushort8v a = *(const ushort8v*)(ap + k0);
      ushort8v b = *(const ushort8v*)(bp + k0);
      acc = __builtin_amdgcn_mfma_f32_16x16x32_bf16(asbf(a), asbf(b), acc, 0, 0, 0);
    }
  } else {
    const float* apf = (const float*)X + arow;
#pragma unroll
    for (int k0 = 0; k0 < HID; k0 += 32) {
      floatx4 f0 = *(const floatx4*)(apf + k0);
      floatx4 f1 = *(const floatx4*)(apf + k0 + 4);
      ushort8v a;
#pragma unroll
      for (int i = 0; i < 4; ++i) { a[i] = f2bf(f0[i]); a[4 + i] = f2bf(f1[i]); }
      ushort8v b = *(const ushort8v*)(bp + k0);
      acc = __builtin_amdgcn_mfma_f32_16x16x32_bf16(asbf(a), asbf(b), acc, 0, 0, 0);
    }
  }
  float bv = biasF[tn * 16 + id];
  int row0 = tm * 16 + quad * 4;
  int col  = tn * 16 + id;
#pragma unroll
  for (int r = 0; r < 4; ++r)
    Y[(row0 + r) * HID + col] = f2bf(acc[r] + bv);
}

// ---------- GEMM output proj (round-2 proven) ----------
__global__ __launch_bounds__(256) void gemm_out(
    const ushort_t* __restrict__ X, const ushort_t* __restrict__ Wt,
    const float* __restrict__ biasF, void* __restrict__ out,
    const int* __restrict__ flag) {
  const int isbf = flag[0];
  int wave = (blockIdx.x << 2) + (threadIdx.x >> 6);
  int lane = threadIdx.x & 63;
  int id = lane & 15, quad = lane >> 4;
  int tn = wave & 31, tm = wave >> 5;
  const ushort_t* ap = X  + (long)(tm * 16 + id) * HID + quad * 8;
  const ushort_t* bp = Wt + (tn * 16 + id) * HID + quad * 8;
  floatx4 acc = {0.f, 0.f, 0.f, 0.f};
#pragma unroll
  for (int k0 = 0; k0 < HID; k0 += 32) {
    ushort8v a = *(const ushort8v*)(ap + k0);
    ushort8v b = *(const ushort8v*)(bp + k0);
    acc = __builtin_amdgcn_mfma_f32_16x16x32_bf16(asbf(a), asbf(b), acc, 0, 0, 0);
  }
  float bv = biasF[tn * 16 + id];
  int row0 = tm * 16 + quad * 4;
  int col  = tn * 16 + id;
  if (isbf) {
    ushort_t* o = (ushort_t*)out;
#pragma unroll
    for (int r = 0; r < 4; ++r) o[(row0 + r) * HID + col] = f2bf(acc[r] + bv);
  } else {
    float* o = (float*)out;
#pragma unroll
    for (int r = 0; r < 4; ++r) o[(row0 + r) * HID + col] = acc[r] + bv;
  }
}

// ---------- flash attention — S^T version UNDER TEST (round-4 text) ----------
__global__ __launch_bounds__(256) void flash_attn(
    const ushort_t* __restrict__ Q, const ushort_t* __restrict__ K,
    const ushort_t* __restrict__ V, const int* __restrict__ mask,
    ushort_t* __restrict__ ctx) {
  const int qblk = blockIdx.x, h = blockIdx.y, b = blockIdx.z;
  const int tid = threadIdx.x;
  const int wid = tid >> 6, lane = tid & 63;
  const int id = lane & 15, quad = lane >> 4;

  __shared__ ushort_t Kt[64 * 72];       // [key][d] stride 72
  __shared__ ushort_t Vt[64 * 72];       // [d][key] stride 72 (transposed)
  __shared__ ushort_t Pl[4][32 * 72];    // per-wave P as [q][key] stride 72

  const ushort_t* Qb = Q + (long)(b * SEQ + qblk * 128 + wid * 32) * HID + h * HD;
  const ushort_t* Kb = K + (long)(b * SEQ) * HID + h * HD;
  const ushort_t* Vb = V + (long)(b * SEQ) * HID + h * HD;
  const int* mrow = mask + b * SEQ;

  ushort8v qf[2][2];
#pragma unroll
  for (int qs = 0; qs < 2; ++qs)
#pragma unroll
    for (int kh = 0; kh < 2; ++kh)
      qf[qs][kh] = *(const ushort8v*)(Qb + (qs * 16 + id) * HID + kh * 32 + quad * 8);

  floatx4 o[4][2];
  float m_i[2] = {-1e30f, -1e30f}, l_i[2] = {0.f, 0.f};
#pragma unroll
  for (int dg = 0; dg < 4; ++dg) { o[dg][0] = (floatx4){0,0,0,0}; o[dg][1] = (floatx4){0,0,0,0}; }

  const int skey = tid >> 2;             // 0..63
  const int sdc  = (tid & 3) * 16;       // 0,16,32,48

  for (int kb = 0; kb < SEQ / 64; ++kb) {
    {
      const ushort_t* kp = Kb + (long)(kb * 64 + skey) * HID + sdc;
      const ushort_t* vp = Vb + (long)(kb * 64 + skey) * HID + sdc;
      ushort8v k0v = *(const ushort8v*)(kp);
      ushort8v k1v = *(const ushort8v*)(kp + 8);
      ushort8v v0v = *(const ushort8v*)(vp);
      ushort8v v1v = *(const ushort8v*)(vp + 8);
      *(ushort8v*)(&Kt[skey * 72 + sdc])     = k0v;
      *(ushort8v*)(&Kt[skey * 72 + sdc + 8]) = k1v;
#pragma unroll
      for (int i = 0; i < 8; ++i) Vt[(sdc + i) * 72 + skey] = v0v[i];
#pragma unroll
      for (int i = 0; i < 8; ++i) Vt[(sdc + 8 + i) * 72 + skey] = v1v[i];
    }
    __syncthreads();

    floatx4 st[2][4];
#pragma unroll
    for (int ks = 0; ks < 4; ++ks) {
      ushort8v kf0 = *(const ushort8v*)(&Kt[(ks * 16 + id) * 72 + quad * 8]);
      ushort8v kf1 = *(const ushort8v*)(&Kt[(ks * 16 + id) * 72 + 32 + quad * 8]);
#pragma unroll
      for (int qs = 0; qs < 2; ++qs) {
        floatx4 a = (floatx4){0,0,0,0};
        a = __builtin_amdgcn_mfma_f32_16x16x32_bf16(asbf(kf0), asbf(qf[qs][0]), a, 0, 0, 0);
        a = __builtin_amdgcn_mfma_f32_16x16x32_bf16(asbf(kf1), asbf(qf[qs][1]), a, 0, 0, 0);
        st[qs][ks] = a;
      }
    }
#pragma unroll
    for (int ks = 0; ks < 4; ++ks) {
      intx4 mv = *(const intx4*)(mrow + kb * 64 + ks * 16 + quad * 4);
#pragma unroll
      for (int r = 0; r < 4; ++r) {
        float s0 = st[0][ks][r] * 0.125f, s1 = st[1][ks][r] * 0.125f;
        st[0][ks][r] = mv[r] ? s0 : -1e9f;
        st[1][ks][r] = mv[r] ? s1 : -1e9f;
      }
    }
#pragma unroll
    for (int qs = 0; qs < 2; ++qs) {
      float mx = st[qs][0][0];
#pragma unroll
      for (int ks = 0; ks < 4; ++ks)
#pragma unroll
        for (int r = 0; r < 4; ++r) mx = fmaxf(mx, st[qs][ks][r]);
      mx = fmaxf(mx, __shfl_xor(mx, 16));
      mx = fmaxf(mx, __shfl_xor(mx, 32));
      float mnew = fmaxf(m_i[qs], mx);
      float alpha = __expf(m_i[qs] - mnew);
      float rs = 0.f;
#pragma unroll
      for (int ks = 0; ks < 4; ++ks) {
        ushort4v pk;
#pragma unroll
        for (int r = 0; r < 4; ++r) {
          float p = __expf(st[qs][ks][r] - mnew);
          rs += p;
          pk[r] = f2bf(p);
        }
        *(ushort4v*)(&Pl[wid][(qs * 16 + id) * 72 + ks * 16 + quad * 4]) = pk;
      }
      rs += __shfl_xor(rs, 16);
      rs += __shfl_xor(rs, 32);
      l_i[qs] = l_i[qs] * alpha + rs;
      m_i[qs] = mnew;
#pragma unroll
      for (int dg = 0; dg < 4; ++dg) o[dg][qs] *= alpha;
    }
    __syncthreads();   // P visible before PV reads

#pragma unroll
    for (int kc = 0; kc < 2; ++kc) {
      ushort8v pf0 = *(const ushort8v*)(&Pl[wid][(0 * 16 + id) * 72 + kc * 32 + quad * 8]);
      ushort8v pf1 = *(const ushort8v*)(&Pl[wid][(1 * 16 + id) * 72 + kc * 32 + quad * 8]);
#pragma unroll
      for (int dg = 0; dg < 4; ++dg) {
        ushort8v vf = *(const ushort8v*)(&Vt[(dg * 16 + id) * 72 + kc * 32 + quad * 8]);
        o[dg][0] = __builtin_amdgcn_mfma_f32_16x16x32_bf16(asbf(vf), asbf(pf0), o[dg][0], 0, 0, 0);
        o[dg][1] = __builtin_amdgcn_mfma_f32_16x16x32_bf16(asbf(vf), asbf(pf1), o[dg][1], 0, 0, 0);
      }
    }
    __syncthreads();
  }

#pragma unroll
  for (int qs = 0; qs < 2; ++qs) {
    float inv = 1.0f / l_i[qs];
    long qrow = (long)(b * SEQ + qblk * 128 + wid * 32 + qs * 16 + id);
#pragma unroll
    for (int dg = 0; dg < 4; ++dg) {
      ushort4v pk;
#pragma unroll
      for (int r = 0; r < 4; ++r) pk[r] = f2bf(o[dg][qs][r] * inv);
      *(ushort4v*)(&ctx[qrow * HID + h * HD + dg * 16 + quad * 4]) = pk;
    }
  }
}

extern "C" void kernel_launch(void* const* d_in, const int* in_sizes, int n_in,
                              void* d_out, int out_size, void* d_ws, size_t ws_size,
                              hipStream_t stream) {
  const void* values = d_in[0];
  const void* keys   = d_in[1];
  const void* query  = d_in[2];
  const int*  mask   = (const int*)d_in[3];
  const void* Wq = d_in[4];  const void* bq = d_in[5];
  const void* Wk = d_in[6];  const void* bk = d_in[7];
  const void* Wv = d_in[8];  const void* bv = d_in[9];
  const void* Wo = d_in[10]; const void* bo = d_in[11];

  ushort_t* ws = (ushort_t*)d_ws;
  const size_t NEL = (size_t)MTOT * HID;
  ushort_t* Qp  = ws;
  ushort_t* Kp  = ws + NEL;
  ushort_t* Vp  = ws + 2 * NEL;
  ushort_t* Cp  = ws + 3 * NEL;
  ushort_t* WqT = ws + 4 * NEL;
  ushort_t* WkT = WqT + (size_t)HID * HID;
  ushort_t* WvT = WkT + (size_t)HID * HID;
  ushort_t* WoT = WvT + (size_t)HID * HID;
  float* biasF  = (float*)(WoT + (size_t)HID * HID);
  int* flag     = (int*)(biasF + 4 * HID);

  detect_dtype<<<1, 64, 0, stream>>>((const unsigned int*)query, flag);
  prep_w<<<dim3(1024, 4), 256, 0, stream>>>(Wq, Wk, Wv, Wo, WqT, WkT, WvT, WoT, flag);
  prep_b<<<8, 256, 0, stream>>>(bq, bk, bv, bo, biasF, flag);

  const int gemm_blocks = (MTOT / 16) * (HID / 16) / 4;  // 4096
  gemm_in<<<gemm_blocks, 256, 0, stream>>>(query,  WqT, biasF + 0 * HID, Qp, flag);
  gemm_in<<<gemm_blocks, 256, 0, stream>>>(keys,   WkT, biasF + 1 * HID, Kp, flag);
  gemm_in<<<gemm_blocks, 256, 0, stream>>>(values, WvT, biasF + 2 * HID, Vp, flag);

  flash_attn<<<dim3(SEQ / 128, NH, BATCH), 256, 0, stream>>>(Qp, Kp, Vp, mask, Cp);

  gemm_out<<<gemm_blocks, 256, 0, stream>>>(Cp, WoT, biasF + 3 * HID, d_out, flag);
}

// Round 8
// 331.330 us; speedup vs baseline: 1.9958x; 1.5920x over previous
//
#include <hip/hip_runtime.h>

#define HID 512
#define NH 8
#define HD 64
#define BATCH 4
#define SEQ 2048
#define MTOT (BATCH * SEQ)   // 8192

typedef unsigned short ushort_t;
typedef __bf16 bf16x8 __attribute__((ext_vector_type(8)));
typedef unsigned short ushort8v __attribute__((ext_vector_type(8)));
typedef unsigned short ushort4v __attribute__((ext_vector_type(4)));
typedef float floatx4 __attribute__((ext_vector_type(4)));
typedef int intx4 __attribute__((ext_vector_type(4)));

static __device__ __forceinline__ unsigned short f2bf(float f) {
  union { float f; unsigned int u; } c; c.f = f;
  unsigned int u = c.u;
  u += 0x7fff + ((u >> 16) & 1);   // RNE
  return (unsigned short)(u >> 16);
}
static __device__ __forceinline__ float bf2f(unsigned short s) {
  union { unsigned int u; float f; } c; c.u = ((unsigned int)s) << 16;
  return c.f;
}
static __device__ __forceinline__ bf16x8 asbf(ushort8v v) {
  return __builtin_bit_cast(bf16x8, v);
}

// ---------- dtype detector (proven) ----------
__global__ void detect_dtype(const unsigned int* __restrict__ q, int* __restrict__ flag) {
  if (threadIdx.x == 0 && blockIdx.x == 0) {
    int hits = 0;
    for (int i = 0; i < 256; ++i) {
      unsigned e = (q[i] >> 7) & 0xff;
      hits += (e >= 110 && e <= 136) ? 1 : 0;
    }
    flag[0] = (hits >= 128) ? 1 : 0;
  }
}

// ---------- weight transpose+convert (proven) ----------
__global__ __launch_bounds__(256) void prep_w(
    const void* __restrict__ W0, const void* __restrict__ W1,
    const void* __restrict__ W2, const void* __restrict__ W3,
    ushort_t* __restrict__ T0, ushort_t* __restrict__ T1,
    ushort_t* __restrict__ T2, ushort_t* __restrict__ T3,
    const int* __restrict__ flag) {
  const int isbf = flag[0];
  const void* W; ushort_t* T;
  switch (blockIdx.y) {
    case 0: W = W0; T = T0; break;
    case 1: W = W1; T = T1; break;
    case 2: W = W2; T = T2; break;
    default: W = W3; T = T3; break;
  }
  int idx = blockIdx.x * 256 + threadIdx.x;
  int k = idx >> 9, n = idx & 511;
  ushort_t v = isbf ? ((const ushort_t*)W)[k * HID + n]
                    : f2bf(((const float*)W)[k * HID + n]);
  T[n * HID + k] = v;
}

// ---------- bias convert (proven) ----------
__global__ __launch_bounds__(256) void prep_b(
    const void* __restrict__ B0, const void* __restrict__ B1,
    const void* __restrict__ B2, const void* __restrict__ B3,
    float* __restrict__ biasF, const int* __restrict__ flag) {
  const int isbf = flag[0];
  int i = blockIdx.x * 256 + threadIdx.x;
  int t = i >> 9, j = i & 511;
  const void* B = (t == 0) ? B0 : (t == 1) ? B1 : (t == 2) ? B2 : B3;
  biasF[i] = isbf ? bf2f(((const ushort_t*)B)[j]) : ((const float*)B)[j];
}

// ---------- register-blocked GEMM (input proj): Y bf16 = X @ Wt^T + bias ----------
// Wave tile 32(M)x64(N): 2 A-frags, 4 B-frags, 8 MFMAs per K=32 step.
// Block = 4 waves as 2x2 -> 64(M)x128(N) tile. grid (M/64, N/128) = (128, 4).
// No LDS, no z-fusion, single-tensor signature (round-3 landmine avoided).
__global__ __launch_bounds__(256) void gemm_rb_in(
    const void* __restrict__ X, const ushort_t* __restrict__ Wt,
    const float* __restrict__ biasF, ushort_t* __restrict__ Y,
    const int* __restrict__ flag) {
  const int isbf = flag[0];
  const int tid = threadIdx.x;
  const int wid = tid >> 6, lane = tid & 63;
  const int id = lane & 15, quad = lane >> 4;
  const int wm = wid >> 1, wn = wid & 1;
  const int m0 = blockIdx.x * 64 + wm * 32;
  const int n0 = blockIdx.y * 128 + wn * 64;

  floatx4 acc[2][4];
#pragma unroll
  for (int i = 0; i < 2; ++i)
#pragma unroll
    for (int j = 0; j < 4; ++j) acc[i][j] = (floatx4){0.f, 0.f, 0.f, 0.f};

  const ushort_t* bp = Wt + (long)(n0 + id) * HID + quad * 8;
  if (isbf) {
    const ushort_t* ap = (const ushort_t*)X + (long)(m0 + id) * HID + quad * 8;
#pragma unroll
    for (int k0 = 0; k0 < HID; k0 += 32) {
      ushort8v a[2], b[4];
#pragma unroll
      for (int ms = 0; ms < 2; ++ms) a[ms] = *(const ushort8v*)(ap + (long)ms * 16 * HID + k0);
#pragma unroll
      for (int ns = 0; ns < 4; ++ns) b[ns] = *(const ushort8v*)(bp + (long)ns * 16 * HID + k0);
#pragma unroll
      for (int ms = 0; ms < 2; ++ms)
#pragma unroll
        for (int ns = 0; ns < 4; ++ns)
          acc[ms][ns] = __builtin_amdgcn_mfma_f32_16x16x32_bf16(asbf(a[ms]), asbf(b[ns]), acc[ms][ns], 0, 0, 0);
    }
  } else {
    const float* apf = (const float*)X + (long)(m0 + id) * HID + quad * 8;
#pragma unroll
    for (int k0 = 0; k0 < HID; k0 += 32) {
      ushort8v a[2], b[4];
#pragma unroll
      for (int ms = 0; ms < 2; ++ms) {
        floatx4 f0 = *(const floatx4*)(apf + (long)ms * 16 * HID + k0);
        floatx4 f1 = *(const floatx4*)(apf + (long)ms * 16 * HID + k0 + 4);
#pragma unroll
        for (int i = 0; i < 4; ++i) { a[ms][i] = f2bf(f0[i]); a[ms][4 + i] = f2bf(f1[i]); }
      }
#pragma unroll
      for (int ns = 0; ns < 4; ++ns) b[ns] = *(const ushort8v*)(bp + (long)ns * 16 * HID + k0);
#pragma unroll
      for (int ms = 0; ms < 2; ++ms)
#pragma unroll
        for (int ns = 0; ns < 4; ++ns)
          acc[ms][ns] = __builtin_amdgcn_mfma_f32_16x16x32_bf16(asbf(a[ms]), asbf(b[ns]), acc[ms][ns], 0, 0, 0);
    }
  }
#pragma unroll
  for (int ns = 0; ns < 4; ++ns) {
    float bv = biasF[n0 + ns * 16 + id];
    int col = n0 + ns * 16 + id;
#pragma unroll
    for (int ms = 0; ms < 2; ++ms) {
      int row0 = m0 + ms * 16 + quad * 4;
#pragma unroll
      for (int r = 0; r < 4; ++r)
        Y[(long)(row0 + r) * HID + col] = f2bf(acc[ms][ns][r] + bv);
    }
  }
}

// ---------- register-blocked GEMM (output proj): out = Cp @ WoT^T + bo ----------
__global__ __launch_bounds__(256) void gemm_rb_out(
    const ushort_t* __restrict__ X, const ushort_t* __restrict__ Wt,
    const float* __restrict__ biasF, void* __restrict__ out,
    const int* __restrict__ flag) {
  const int isbf = flag[0];
  const int tid = threadIdx.x;
  const int wid = tid >> 6, lane = tid & 63;
  const int id = lane & 15, quad = lane >> 4;
  const int wm = wid >> 1, wn = wid & 1;
  const int m0 = blockIdx.x * 64 + wm * 32;
  const int n0 = blockIdx.y * 128 + wn * 64;

  floatx4 acc[2][4];
#pragma unroll
  for (int i = 0; i < 2; ++i)
#pragma unroll
    for (int j = 0; j < 4; ++j) acc[i][j] = (floatx4){0.f, 0.f, 0.f, 0.f};

  const ushort_t* ap = X  + (long)(m0 + id) * HID + quad * 8;
  const ushort_t* bp = Wt + (long)(n0 + id) * HID + quad * 8;
#pragma unroll
  for (int k0 = 0; k0 < HID; k0 += 32) {
    ushort8v a[2], b[4];
#pragma unroll
    for (int ms = 0; ms < 2; ++ms) a[ms] = *(const ushort8v*)(ap + (long)ms * 16 * HID + k0);
#pragma unroll
    for (int ns = 0; ns < 4; ++ns) b[ns] = *(const ushort8v*)(bp + (long)ns * 16 * HID + k0);
#pragma unroll
    for (int ms = 0; ms < 2; ++ms)
#pragma unroll
      for (int ns = 0; ns < 4; ++ns)
        acc[ms][ns] = __builtin_amdgcn_mfma_f32_16x16x32_bf16(asbf(a[ms]), asbf(b[ns]), acc[ms][ns], 0, 0, 0);
  }
#pragma unroll
  for (int ns = 0; ns < 4; ++ns) {
    float bv = biasF[n0 + ns * 16 + id];
    int col = n0 + ns * 16 + id;
#pragma unroll
    for (int ms = 0; ms < 2; ++ms) {
      int row0 = m0 + ms * 16 + quad * 4;
      if (isbf) {
        ushort_t* o = (ushort_t*)out;
#pragma unroll
        for (int r = 0; r < 4; ++r) o[(long)(row0 + r) * HID + col] = f2bf(acc[ms][ns][r] + bv);
      } else {
        float* o = (float*)out;
#pragma unroll
        for (int r = 0; r < 4; ++r) o[(long)(row0 + r) * HID + col] = acc[ms][ns][r] + bv;
      }
    }
  }
}

// ---------- flash attention — S^T version (round-6 proven, verbatim) ----------
__global__ __launch_bounds__(256) void flash_attn(
    const ushort_t* __restrict__ Q, const ushort_t* __restrict__ K,
    const ushort_t* __restrict__ V, const int* __restrict__ mask,
    ushort_t* __restrict__ ctx) {
  const int qblk = blockIdx.x, h = blockIdx.y, b = blockIdx.z;
  const int tid = threadIdx.x;
  const int wid = tid >> 6, lane = tid & 63;
  const int id = lane & 15, quad = lane >> 4;

  __shared__ ushort_t Kt[64 * 72];       // [key][d] stride 72
  __shared__ ushort_t Vt[64 * 72];       // [d][key] stride 72 (transposed)
  __shared__ ushort_t Pl[4][32 * 72];    // per-wave P as [q][key] stride 72

  const ushort_t* Qb = Q + (long)(b * SEQ + qblk * 128 + wid * 32) * HID + h * HD;
  const ushort_t* Kb = K + (long)(b * SEQ) * HID + h * HD;
  const ushort_t* Vb = V + (long)(b * SEQ) * HID + h * HD;
  const int* mrow = mask + b * SEQ;

  ushort8v qf[2][2];
#pragma unroll
  for (int qs = 0; qs < 2; ++qs)
#pragma unroll
    for (int kh = 0; kh < 2; ++kh)
      qf[qs][kh] = *(const ushort8v*)(Qb + (qs * 16 + id) * HID + kh * 32 + quad * 8);

  floatx4 o[4][2];
  float m_i[2] = {-1e30f, -1e30f}, l_i[2] = {0.f, 0.f};
#pragma unroll
  for (int dg = 0; dg < 4; ++dg) { o[dg][0] = (floatx4){0,0,0,0}; o[dg][1] = (floatx4){0,0,0,0}; }

  const int skey = tid >> 2;             // 0..63
  const int sdc  = (tid & 3) * 16;       // 0,16,32,48

  for (int kb = 0; kb < SEQ / 64; ++kb) {
    {
      const ushort_t* kp = Kb + (long)(kb * 64 + skey) * HID + sdc;
      const ushort_t* vp = Vb + (long)(kb * 64 + skey) * HID + sdc;
      ushort8v k0v = *(const ushort8v*)(kp);
      ushort8v k1v = *(const ushort8v*)(kp + 8);
      ushort8v v0v = *(const ushort8v*)(vp);
      ushort8v v1v = *(const ushort8v*)(vp + 8);
      *(ushort8v*)(&Kt[skey * 72 + sdc])     = k0v;
      *(ushort8v*)(&Kt[skey * 72 + sdc + 8]) = k1v;
#pragma unroll
      for (int i = 0; i < 8; ++i) Vt[(sdc + i) * 72 + skey] = v0v[i];
#pragma unroll
      for (int i = 0; i < 8; ++i) Vt[(sdc + 8 + i) * 72 + skey] = v1v[i];
    }
    __syncthreads();

    floatx4 st[2][4];
#pragma unroll
    for (int ks = 0; ks < 4; ++ks) {
      ushort8v kf0 = *(const ushort8v*)(&Kt[(ks * 16 + id) * 72 + quad * 8]);
      ushort8v kf1 = *(const ushort8v*)(&Kt[(ks * 16 + id) * 72 + 32 + quad * 8]);
#pragma unroll
      for (int qs = 0; qs < 2; ++qs) {
        floatx4 a = (floatx4){0,0,0,0};
        a = __builtin_amdgcn_mfma_f32_16x16x32_bf16(asbf(kf0), asbf(qf[qs][0]), a, 0, 0, 0);
        a = __builtin_amdgcn_mfma_f32_16x16x32_bf16(asbf(kf1), asbf(qf[qs][1]), a, 0, 0, 0);
        st[qs][ks] = a;
      }
    }
#pragma unroll
    for (int ks = 0; ks < 4; ++ks) {
      intx4 mv = *(const intx4*)(mrow + kb * 64 + ks * 16 + quad * 4);
#pragma unroll
      for (int r = 0; r < 4; ++r) {
        float s0 = st[0][ks][r] * 0.125f, s1 = st[1][ks][r] * 0.125f;
        st[0][ks][r] = mv[r] ? s0 : -1e9f;
        st[1][ks][r] = mv[r] ? s1 : -1e9f;
      }
    }
#pragma unroll
    for (int qs = 0; qs < 2; ++qs) {
      float mx = st[qs][0][0];
#pragma unroll
      for (int ks = 0; ks < 4; ++ks)
#pragma unroll
        for (int r = 0; r < 4; ++r) mx = fmaxf(mx, st[qs][ks][r]);
      mx = fmaxf(mx, __shfl_xor(mx, 16));
      mx = fmaxf(mx, __shfl_xor(mx, 32));
      float mnew = fmaxf(m_i[qs], mx);
      float alpha = __expf(m_i[qs] - mnew);
      float rs = 0.f;
#pragma unroll
      for (int ks = 0; ks < 4; ++ks) {
        ushort4v pk;
#pragma unroll
        for (int r = 0; r < 4; ++r) {
          float p = __expf(st[qs][ks][r] - mnew);
          rs += p;
          pk[r] = f2bf(p);
        }
        *(ushort4v*)(&Pl[wid][(qs * 16 + id) * 72 + ks * 16 + quad * 4]) = pk;
      }
      rs += __shfl_xor(rs, 16);
      rs += __shfl_xor(rs, 32);
      l_i[qs] = l_i[qs] * alpha + rs;
      m_i[qs] = mnew;
#pragma unroll
      for (int dg = 0; dg < 4; ++dg) o[dg][qs] *= alpha;
    }
    __syncthreads();   // P visible before PV reads

#pragma unroll
    for (int kc = 0; kc < 2; ++kc) {
      ushort8v pf0 = *(const ushort8v*)(&Pl[wid][(0 * 16 + id) * 72 + kc * 32 + quad * 8]);
      ushort8v pf1 = *(const ushort8v*)(&Pl[wid][(1 * 16 + id) * 72 + kc * 32 + quad * 8]);
#pragma unroll
      for (int dg = 0; dg < 4; ++dg) {
        ushort8v vf = *(const ushort8v*)(&Vt[(dg * 16 + id) * 72 + kc * 32 + quad * 8]);
        o[dg][0] = __builtin_amdgcn_mfma_f32_16x16x32_bf16(asbf(vf), asbf(pf0), o[dg][0], 0, 0, 0);
        o[dg][1] = __builtin_amdgcn_mfma_f32_16x16x32_bf16(asbf(vf), asbf(pf1), o[dg][1], 0, 0, 0);
      }
    }
    __syncthreads();
  }

#pragma unroll
  for (int qs = 0; qs < 2; ++qs) {
    float inv = 1.0f / l_i[qs];
    long qrow = (long)(b * SEQ + qblk * 128 + wid * 32 + qs * 16 + id);
#pragma unroll
    for (int dg = 0; dg < 4; ++dg) {
      ushort4v pk;
#pragma unroll
      for (int r = 0; r < 4; ++r) pk[r] = f2bf(o[dg][qs][r] * inv);
      *(ushort4v*)(&ctx[qrow * HID + h * HD + dg * 16 + quad * 4]) = pk;
    }
  }
}

extern "C" void kernel_launch(void* const* d_in, const int* in_sizes, int n_in,
                              void* d_out, int out_size, void* d_ws, size_t ws_size,
                              hipStream_t stream) {
  const void* values = d_in[0];
  const void* keys   = d_in[1];
  const void* query  = d_in[2];
  const int*  mask   = (const int*)d_in[3];
  const void* Wq = d_in[4];  const void* bq = d_in[5];
  const void* Wk = d_in[6];  const void* bk = d_in[7];
  const void* Wv = d_in[8];  const void* bv = d_in[9];
  const void* Wo = d_in[10]; const void* bo = d_in[11];

  ushort_t* ws = (ushort_t*)d_ws;
  const size_t NEL = (size_t)MTOT * HID;
  ushort_t* Qp  = ws;
  ushort_t* Kp  = ws + NEL;
  ushort_t* Vp  = ws + 2 * NEL;
  ushort_t* Cp  = ws + 3 * NEL;
  ushort_t* WqT = ws + 4 * NEL;
  ushort_t* WkT = WqT + (size_t)HID * HID;
  ushort_t* WvT = WkT + (size_t)HID * HID;
  ushort_t* WoT = WvT + (size_t)HID * HID;
  float* biasF  = (float*)(WoT + (size_t)HID * HID);
  int* flag     = (int*)(biasF + 4 * HID);

  detect_dtype<<<1, 64, 0, stream>>>((const unsigned int*)query, flag);
  prep_w<<<dim3(1024, 4), 256, 0, stream>>>(Wq, Wk, Wv, Wo, WqT, WkT, WvT, WoT, flag);
  prep_b<<<8, 256, 0, stream>>>(bq, bk, bv, bo, biasF, flag);

  const dim3 ggrid(MTOT / 64, HID / 128);   // (128, 4)
  gemm_rb_in<<<ggrid, 256, 0, stream>>>(query,  WqT, biasF + 0 * HID, Qp, flag);
  gemm_rb_in<<<ggrid, 256, 0, stream>>>(keys,   WkT, biasF + 1 * HID, Kp, flag);
  gemm_rb_in<<<ggrid, 256, 0, stream>>>(values, WvT, biasF + 2 * HID, Vp, flag);

  flash_attn<<<dim3(SEQ / 128, NH, BATCH), 256, 0, stream>>>(Qp, Kp, Vp, mask, Cp);

  gemm_rb_out<<<ggrid, 256, 0, stream>>>(Cp, WoT, biasF + 3 * HID, d_out, flag);
}

// Round 9
// 268.857 us; speedup vs baseline: 2.4595x; 1.2324x over previous
//
#include <hip/hip_runtime.h>

#define HID 512
#define NH 8
#define HD 64
#define BATCH 4
#define SEQ 2048
#define MTOT (BATCH * SEQ)   // 8192

typedef unsigned short ushort_t;
typedef __bf16 bf16x8 __attribute__((ext_vector_type(8)));
typedef unsigned short ushort8v __attribute__((ext_vector_type(8)));
typedef unsigned short ushort4v __attribute__((ext_vector_type(4)));
typedef float floatx4 __attribute__((ext_vector_type(4)));
typedef int intx4 __attribute__((ext_vector_type(4)));

static __device__ __forceinline__ unsigned short f2bf(float f) {
  union { float f; unsigned int u; } c; c.f = f;
  unsigned int u = c.u;
  u += 0x7fff + ((u >> 16) & 1);   // RNE
  return (unsigned short)(u >> 16);
}
static __device__ __forceinline__ float bf2f(unsigned short s) {
  union { unsigned int u; float f; } c; c.u = ((unsigned int)s) << 16;
  return c.f;
}
static __device__ __forceinline__ bf16x8 asbf(ushort8v v) {
  return __builtin_bit_cast(bf16x8, v);
}

// ---------- dtype detector (proven) ----------
__global__ void detect_dtype(const unsigned int* __restrict__ q, int* __restrict__ flag) {
  if (threadIdx.x == 0 && blockIdx.x == 0) {
    int hits = 0;
    for (int i = 0; i < 256; ++i) {
      unsigned e = (q[i] >> 7) & 0xff;
      hits += (e >= 110 && e <= 136) ? 1 : 0;
    }
    flag[0] = (hits >= 128) ? 1 : 0;
  }
}

// ---------- weight transpose+convert (proven) ----------
__global__ __launch_bounds__(256) void prep_w(
    const void* __restrict__ W0, const void* __restrict__ W1,
    const void* __restrict__ W2, const void* __restrict__ W3,
    ushort_t* __restrict__ T0, ushort_t* __restrict__ T1,
    ushort_t* __restrict__ T2, ushort_t* __restrict__ T3,
    const int* __restrict__ flag) {
  const int isbf = flag[0];
  const void* W; ushort_t* T;
  switch (blockIdx.y) {
    case 0: W = W0; T = T0; break;
    case 1: W = W1; T = T1; break;
    case 2: W = W2; T = T2; break;
    default: W = W3; T = T3; break;
  }
  int idx = blockIdx.x * 256 + threadIdx.x;
  int k = idx >> 9, n = idx & 511;
  ushort_t v = isbf ? ((const ushort_t*)W)[k * HID + n]
                    : f2bf(((const float*)W)[k * HID + n]);
  T[n * HID + k] = v;
}

// ---------- bias convert (proven) ----------
__global__ __launch_bounds__(256) void prep_b(
    const void* __restrict__ B0, const void* __restrict__ B1,
    const void* __restrict__ B2, const void* __restrict__ B3,
    float* __restrict__ biasF, const int* __restrict__ flag) {
  const int isbf = flag[0];
  int i = blockIdx.x * 256 + threadIdx.x;
  int t = i >> 9, j = i & 511;
  const void* B = (t == 0) ? B0 : (t == 1) ? B1 : (t == 2) ? B2 : B3;
  biasF[i] = isbf ? bf2f(((const ushort_t*)B)[j]) : ((const float*)B)[j];
}

// ---------- LDS-staged GEMM (input proj): Y bf16 = X @ Wt^T + bias ----------
// Tile 64(M)x128(N), BK=64. 4 waves as 2x2; wave tile 32x64 (2x4 frags).
// Coalesced staging: 8 lanes per row (128B runs). LDS stride 72 (b128-clean).
// Single-tensor signature: no z-fusion, no aliased __restrict__.
__global__ __launch_bounds__(256) void gemm_lds_in(
    const void* __restrict__ X, const ushort_t* __restrict__ Wt,
    const float* __restrict__ biasF, ushort_t* __restrict__ Y,
    const int* __restrict__ flag) {
  const int isbf = flag[0];
  const int tid = threadIdx.x;
  const int wid = tid >> 6, lane = tid & 63;
  const int id = lane & 15, quad = lane >> 4;
  const int wm = wid >> 1, wn = wid & 1;
  const int m0 = blockIdx.x * 64, n0 = blockIdx.y * 128;

  __shared__ ushort_t At[64 * 72];    // [m][k] stride 72
  __shared__ ushort_t Bt[128 * 72];   // [n][k] stride 72

  const int srow = tid >> 3;          // 0..31
  const int scol = (tid & 7) * 8;     // 0..56

  floatx4 acc[2][4];
#pragma unroll
  for (int i = 0; i < 2; ++i)
#pragma unroll
    for (int j = 0; j < 4; ++j) acc[i][j] = (floatx4){0.f, 0.f, 0.f, 0.f};

  for (int k0 = 0; k0 < HID; k0 += 64) {
    ushort8v aR[2], bR[4];
    if (isbf) {
      const ushort_t* ap = (const ushort_t*)X + (long)(m0 + srow) * HID + k0 + scol;
#pragma unroll
      for (int p = 0; p < 2; ++p) aR[p] = *(const ushort8v*)(ap + (long)p * 32 * HID);
    } else {
      const float* apf = (const float*)X + (long)(m0 + srow) * HID + k0 + scol;
#pragma unroll
      for (int p = 0; p < 2; ++p) {
        floatx4 f0 = *(const floatx4*)(apf + (long)p * 32 * HID);
        floatx4 f1 = *(const floatx4*)(apf + (long)p * 32 * HID + 4);
#pragma unroll
        for (int i = 0; i < 4; ++i) { aR[p][i] = f2bf(f0[i]); aR[p][4 + i] = f2bf(f1[i]); }
      }
    }
    {
      const ushort_t* bp = Wt + (long)(n0 + srow) * HID + k0 + scol;
#pragma unroll
      for (int p = 0; p < 4; ++p) bR[p] = *(const ushort8v*)(bp + (long)p * 32 * HID);
    }
    __syncthreads();   // previous iter's LDS reads complete
#pragma unroll
    for (int p = 0; p < 2; ++p) *(ushort8v*)(&At[(srow + 32 * p) * 72 + scol]) = aR[p];
#pragma unroll
    for (int p = 0; p < 4; ++p) *(ushort8v*)(&Bt[(srow + 32 * p) * 72 + scol]) = bR[p];
    __syncthreads();
#pragma unroll
    for (int kk = 0; kk < 64; kk += 32) {
      ushort8v af[2], bf4[4];
#pragma unroll
      for (int ms = 0; ms < 2; ++ms) af[ms] = *(const ushort8v*)(&At[(wm * 32 + ms * 16 + id) * 72 + kk + quad * 8]);
#pragma unroll
      for (int ns = 0; ns < 4; ++ns) bf4[ns] = *(const ushort8v*)(&Bt[(wn * 64 + ns * 16 + id) * 72 + kk + quad * 8]);
#pragma unroll
      for (int ms = 0; ms < 2; ++ms)
#pragma unroll
        for (int ns = 0; ns < 4; ++ns)
          acc[ms][ns] = __builtin_amdgcn_mfma_f32_16x16x32_bf16(asbf(af[ms]), asbf(bf4[ns]), acc[ms][ns], 0, 0, 0);
    }
  }
#pragma unroll
  for (int ns = 0; ns < 4; ++ns) {
    float bv = biasF[n0 + wn * 64 + ns * 16 + id];
    int col = n0 + wn * 64 + ns * 16 + id;
#pragma unroll
    for (int ms = 0; ms < 2; ++ms) {
      int row0 = m0 + wm * 32 + ms * 16 + quad * 4;
#pragma unroll
      for (int r = 0; r < 4; ++r)
        Y[(long)(row0 + r) * HID + col] = f2bf(acc[ms][ns][r] + bv);
    }
  }
}

// ---------- LDS-staged GEMM (output proj): out = Cp @ WoT^T + bo ----------
__global__ __launch_bounds__(256) void gemm_lds_out(
    const ushort_t* __restrict__ X, const ushort_t* __restrict__ Wt,
    const float* __restrict__ biasF, void* __restrict__ out,
    const int* __restrict__ flag) {
  const int isbf = flag[0];
  const int tid = threadIdx.x;
  const int wid = tid >> 6, lane = tid & 63;
  const int id = lane & 15, quad = lane >> 4;
  const int wm = wid >> 1, wn = wid & 1;
  const int m0 = blockIdx.x * 64, n0 = blockIdx.y * 128;

  __shared__ ushort_t At[64 * 72];
  __shared__ ushort_t Bt[128 * 72];

  const int srow = tid >> 3;
  const int scol = (tid & 7) * 8;

  floatx4 acc[2][4];
#pragma unroll
  for (int i = 0; i < 2; ++i)
#pragma unroll
    for (int j = 0; j < 4; ++j) acc[i][j] = (floatx4){0.f, 0.f, 0.f, 0.f};

  for (int k0 = 0; k0 < HID; k0 += 64) {
    ushort8v aR[2], bR[4];
    {
      const ushort_t* ap = X + (long)(m0 + srow) * HID + k0 + scol;
#pragma unroll
      for (int p = 0; p < 2; ++p) aR[p] = *(const ushort8v*)(ap + (long)p * 32 * HID);
      const ushort_t* bp = Wt + (long)(n0 + srow) * HID + k0 + scol;
#pragma unroll
      for (int p = 0; p < 4; ++p) bR[p] = *(const ushort8v*)(bp + (long)p * 32 * HID);
    }
    __syncthreads();
#pragma unroll
    for (int p = 0; p < 2; ++p) *(ushort8v*)(&At[(srow + 32 * p) * 72 + scol]) = aR[p];
#pragma unroll
    for (int p = 0; p < 4; ++p) *(ushort8v*)(&Bt[(srow + 32 * p) * 72 + scol]) = bR[p];
    __syncthreads();
#pragma unroll
    for (int kk = 0; kk < 64; kk += 32) {
      ushort8v af[2], bf4[4];
#pragma unroll
      for (int ms = 0; ms < 2; ++ms) af[ms] = *(const ushort8v*)(&At[(wm * 32 + ms * 16 + id) * 72 + kk + quad * 8]);
#pragma unroll
      for (int ns = 0; ns < 4; ++ns) bf4[ns] = *(const ushort8v*)(&Bt[(wn * 64 + ns * 16 + id) * 72 + kk + quad * 8]);
#pragma unroll
      for (int ms = 0; ms < 2; ++ms)
#pragma unroll
        for (int ns = 0; ns < 4; ++ns)
          acc[ms][ns] = __builtin_amdgcn_mfma_f32_16x16x32_bf16(asbf(af[ms]), asbf(bf4[ns]), acc[ms][ns], 0, 0, 0);
    }
  }
#pragma unroll
  for (int ns = 0; ns < 4; ++ns) {
    float bv = biasF[n0 + wn * 64 + ns * 16 + id];
    int col = n0 + wn * 64 + ns * 16 + id;
#pragma unroll
    for (int ms = 0; ms < 2; ++ms) {
      int row0 = m0 + wm * 32 + ms * 16 + quad * 4;
      if (isbf) {
        ushort_t* o = (ushort_t*)out;
#pragma unroll
        for (int r = 0; r < 4; ++r) o[(long)(row0 + r) * HID + col] = f2bf(acc[ms][ns][r] + bv);
      } else {
        float* o = (float*)out;
#pragma unroll
        for (int r = 0; r < 4; ++r) o[(long)(row0 + r) * HID + col] = acc[ms][ns][r] + bv;
      }
    }
  }
}

// ---------- flash attention — S^T version (round-6 proven, verbatim) ----------
__global__ __launch_bounds__(256) void flash_attn(
    const ushort_t* __restrict__ Q, const ushort_t* __restrict__ K,
    const ushort_t* __restrict__ V, const int* __restrict__ mask,
    ushort_t* __restrict__ ctx) {
  const int qblk = blockIdx.x, h = blockIdx.y, b = blockIdx.z;
  const int tid = threadIdx.x;
  const int wid = tid >> 6, lane = tid & 63;
  const int id = lane & 15, quad = lane >> 4;

  __shared__ ushort_t Kt[64 * 72];       // [key][d] stride 72
  __shared__ ushort_t Vt[64 * 72];       // [d][key] stride 72 (transposed)
  __shared__ ushort_t Pl[4][32 * 72];    // per-wave P as [q][key] stride 72

  const ushort_t* Qb = Q + (long)(b * SEQ + qblk * 128 + wid * 32) * HID + h * HD;
  const ushort_t* Kb = K + (long)(b * SEQ) * HID + h * HD;
  const ushort_t* Vb = V + (long)(b * SEQ) * HID + h * HD;
  const int* mrow = mask + b * SEQ;

  ushort8v qf[2][2];
#pragma unroll
  for (int qs = 0; qs < 2; ++qs)
#pragma unroll
    for (int kh = 0; kh < 2; ++kh)
      qf[qs][kh] = *(const ushort8v*)(Qb + (qs * 16 + id) * HID + kh * 32 + quad * 8);

  floatx4 o[4][2];
  float m_i[2] = {-1e30f, -1e30f}, l_i[2] = {0.f, 0.f};
#pragma unroll
  for (int dg = 0; dg < 4; ++dg) { o[dg][0] = (floatx4){0,0,0,0}; o[dg][1] = (floatx4){0,0,0,0}; }

  const int skey = tid >> 2;             // 0..63
  const int sdc  = (tid & 3) * 16;       // 0,16,32,48

  for (int kb = 0; kb < SEQ / 64; ++kb) {
    {
      const ushort_t* kp = Kb + (long)(kb * 64 + skey) * HID + sdc;
      const ushort_t* vp = Vb + (long)(kb * 64 + skey) * HID + sdc;
      ushort8v k0v = *(const ushort8v*)(kp);
      ushort8v k1v = *(const ushort8v*)(kp + 8);
      ushort8v v0v = *(const ushort8v*)(vp);
      ushort8v v1v = *(const ushort8v*)(vp + 8);
      *(ushort8v*)(&Kt[skey * 72 + sdc])     = k0v;
      *(ushort8v*)(&Kt[skey * 72 + sdc + 8]) = k1v;
#pragma unroll
      for (int i = 0; i < 8; ++i) Vt[(sdc + i) * 72 + skey] = v0v[i];
#pragma unroll
      for (int i = 0; i < 8; ++i) Vt[(sdc + 8 + i) * 72 + skey] = v1v[i];
    }
    __syncthreads();

    floatx4 st[2][4];
#pragma unroll
    for (int ks = 0; ks < 4; ++ks) {
      ushort8v kf0 = *(const ushort8v*)(&Kt[(ks * 16 + id) * 72 + quad * 8]);
      ushort8v kf1 = *(const ushort8v*)(&Kt[(ks * 16 + id) * 72 + 32 + quad * 8]);
#pragma unroll
      for (int qs = 0; qs < 2; ++qs) {
        floatx4 a = (floatx4){0,0,0,0};
        a = __builtin_amdgcn_mfma_f32_16x16x32_bf16(asbf(kf0), asbf(qf[qs][0]), a, 0, 0, 0);
        a = __builtin_amdgcn_mfma_f32_16x16x32_bf16(asbf(kf1), asbf(qf[qs][1]), a, 0, 0, 0);
        st[qs][ks] = a;
      }
    }
#pragma unroll
    for (int ks = 0; ks < 4; ++ks) {
      intx4 mv = *(const intx4*)(mrow + kb * 64 + ks * 16 + quad * 4);
#pragma unroll
      for (int r = 0; r < 4; ++r) {
        float s0 = st[0][ks][r] * 0.125f, s1 = st[1][ks][r] * 0.125f;
        st[0][ks][r] = mv[r] ? s0 : -1e9f;
        st[1][ks][r] = mv[r] ? s1 : -1e9f;
      }
    }
#pragma unroll
    for (int qs = 0; qs < 2; ++qs) {
      float mx = st[qs][0][0];
#pragma unroll
      for (int ks = 0; ks < 4; ++ks)
#pragma unroll
        for (int r = 0; r < 4; ++r) mx = fmaxf(mx, st[qs][ks][r]);
      mx = fmaxf(mx, __shfl_xor(mx, 16));
      mx = fmaxf(mx, __shfl_xor(mx, 32));
      float mnew = fmaxf(m_i[qs], mx);
      float alpha = __expf(m_i[qs] - mnew);
      float rs = 0.f;
#pragma unroll
      for (int ks = 0; ks < 4; ++ks) {
        ushort4v pk;
#pragma unroll
        for (int r = 0; r < 4; ++r) {
          float p = __expf(st[qs][ks][r] - mnew);
          rs += p;
          pk[r] = f2bf(p);
        }
        *(ushort4v*)(&Pl[wid][(qs * 16 + id) * 72 + ks * 16 + quad * 4]) = pk;
      }
      rs += __shfl_xor(rs, 16);
      rs += __shfl_xor(rs, 32);
      l_i[qs] = l_i[qs] * alpha + rs;
      m_i[qs] = mnew;
#pragma unroll
      for (int dg = 0; dg < 4; ++dg) o[dg][qs] *= alpha;
    }
    __syncthreads();   // P visible before PV reads

#pragma unroll
    for (int kc = 0; kc < 2; ++kc) {
      ushort8v pf0 = *(const ushort8v*)(&Pl[wid][(0 * 16 + id) * 72 + kc * 32 + quad * 8]);
      ushort8v pf1 = *(const ushort8v*)(&Pl[wid][(1 * 16 + id) * 72 + kc * 32 + quad * 8]);
#pragma unroll
      for (int dg = 0; dg < 4; ++dg) {
        ushort8v vf = *(const ushort8v*)(&Vt[(dg * 16 + id) * 72 + kc * 32 + quad * 8]);
        o[dg][0] = __builtin_amdgcn_mfma_f32_16x16x32_bf16(asbf(vf), asbf(pf0), o[dg][0], 0, 0, 0);
        o[dg][1] = __builtin_amdgcn_mfma_f32_16x16x32_bf16(asbf(vf), asbf(pf1), o[dg][1], 0, 0, 0);
      }
    }
    __syncthreads();
  }

#pragma unroll
  for (int qs = 0; qs < 2; ++qs) {
    float inv = 1.0f / l_i[qs];
    long qrow = (long)(b * SEQ + qblk * 128 + wid * 32 + qs * 16 + id);
#pragma unroll
    for (int dg = 0; dg < 4; ++dg) {
      ushort4v pk;
#pragma unroll
      for (int r = 0; r < 4; ++r) pk[r] = f2bf(o[dg][qs][r] * inv);
      *(ushort4v*)(&ctx[qrow * HID + h * HD + dg * 16 + quad * 4]) = pk;
    }
  }
}

extern "C" void kernel_launch(void* const* d_in, const int* in_sizes, int n_in,
                              void* d_out, int out_size, void* d_ws, size_t ws_size,
                              hipStream_t stream) {
  const void* values = d_in[0];
  const void* keys   = d_in[1];
  const void* query  = d_in[2];
  const int*  mask   = (const int*)d_in[3];
  const void* Wq = d_in[4];  const void* bq = d_in[5];
  const void* Wk = d_in[6];  const void* bk = d_in[7];
  const void* Wv = d_in[8];  const void* bv = d_in[9];
  const void* Wo = d_in[10]; const void* bo = d_in[11];

  ushort_t* ws = (ushort_t*)d_ws;
  const size_t NEL = (size_t)MTOT * HID;
  ushort_t* Qp  = ws;
  ushort_t* Kp  = ws + NEL;
  ushort_t* Vp  = ws + 2 * NEL;
  ushort_t* Cp  = ws + 3 * NEL;
  ushort_t* WqT = ws + 4 * NEL;
  ushort_t* WkT = WqT + (size_t)HID * HID;
  ushort_t* WvT = WkT + (size_t)HID * HID;
  ushort_t* WoT = WvT + (size_t)HID * HID;
  float* biasF  = (float*)(WoT + (size_t)HID * HID);
  int* flag     = (int*)(biasF + 4 * HID);

  detect_dtype<<<1, 64, 0, stream>>>((const unsigned int*)query, flag);
  prep_w<<<dim3(1024, 4), 256, 0, stream>>>(Wq, Wk, Wv, Wo, WqT, WkT, WvT, WoT, flag);
  prep_b<<<8, 256, 0, stream>>>(bq, bk, bv, bo, biasF, flag);

  const dim3 ggrid(MTOT / 64, HID / 128);   // (128, 4) = 512 blocks
  gemm_lds_in<<<ggrid, 256, 0, stream>>>(query,  WqT, biasF + 0 * HID, Qp, flag);
  gemm_lds_in<<<ggrid, 256, 0, stream>>>(keys,   WkT, biasF + 1 * HID, Kp, flag);
  gemm_lds_in<<<ggrid, 256, 0, stream>>>(values, WvT, biasF + 2 * HID, Vp, flag);

  flash_attn<<<dim3(SEQ / 128, NH, BATCH), 256, 0, stream>>>(Qp, Kp, Vp, mask, Cp);

  gemm_lds_out<<<ggrid, 256, 0, stream>>>(Cp, WoT, biasF + 3 * HID, d_out, flag);
}

// Round 10
// 249.596 us; speedup vs baseline: 2.6493x; 1.0772x over previous
//
#include <hip/hip_runtime.h>

#define HID 512
#define NH 8
#define HD 64
#define BATCH 4
#define SEQ 2048
#define MTOT (BATCH * SEQ)   // 8192

typedef unsigned short ushort_t;
typedef __bf16 bf16x8 __attribute__((ext_vector_type(8)));
typedef unsigned short ushort8v __attribute__((ext_vector_type(8)));
typedef unsigned short ushort4v __attribute__((ext_vector_type(4)));
typedef float floatx4 __attribute__((ext_vector_type(4)));
typedef int intx4 __attribute__((ext_vector_type(4)));

static __device__ __forceinline__ unsigned short f2bf(float f) {
  union { float f; unsigned int u; } c; c.f = f;
  unsigned int u = c.u;
  u += 0x7fff + ((u >> 16) & 1);   // RNE
  return (unsigned short)(u >> 16);
}
static __device__ __forceinline__ float bf2f(unsigned short s) {
  union { unsigned int u; float f; } c; c.u = ((unsigned int)s) << 16;
  return c.f;
}
static __device__ __forceinline__ bf16x8 asbf(ushort8v v) {
  return __builtin_bit_cast(bf16x8, v);
}

// ---------- dtype detector (proven) ----------
__global__ void detect_dtype(const unsigned int* __restrict__ q, int* __restrict__ flag) {
  if (threadIdx.x == 0 && blockIdx.x == 0) {
    int hits = 0;
    for (int i = 0; i < 256; ++i) {
      unsigned e = (q[i] >> 7) & 0xff;
      hits += (e >= 110 && e <= 136) ? 1 : 0;
    }
    flag[0] = (hits >= 128) ? 1 : 0;
  }
}

// ---------- weight transpose+convert (proven) ----------
__global__ __launch_bounds__(256) void prep_w(
    const void* __restrict__ W0, const void* __restrict__ W1,
    const void* __restrict__ W2, const void* __restrict__ W3,
    ushort_t* __restrict__ T0, ushort_t* __restrict__ T1,
    ushort_t* __restrict__ T2, ushort_t* __restrict__ T3,
    const int* __restrict__ flag) {
  const int isbf = flag[0];
  const void* W; ushort_t* T;
  switch (blockIdx.y) {
    case 0: W = W0; T = T0; break;
    case 1: W = W1; T = T1; break;
    case 2: W = W2; T = T2; break;
    default: W = W3; T = T3; break;
  }
  int idx = blockIdx.x * 256 + threadIdx.x;
  int k = idx >> 9, n = idx & 511;
  ushort_t v = isbf ? ((const ushort_t*)W)[k * HID + n]
                    : f2bf(((const float*)W)[k * HID + n]);
  T[n * HID + k] = v;
}

// ---------- bias convert (proven) ----------
__global__ __launch_bounds__(256) void prep_b(
    const void* __restrict__ B0, const void* __restrict__ B1,
    const void* __restrict__ B2, const void* __restrict__ B3,
    float* __restrict__ biasF, const int* __restrict__ flag) {
  const int isbf = flag[0];
  int i = blockIdx.x * 256 + threadIdx.x;
  int t = i >> 9, j = i & 511;
  const void* B = (t == 0) ? B0 : (t == 1) ? B1 : (t == 2) ? B2 : B3;
  biasF[i] = isbf ? bf2f(((const ushort_t*)B)[j]) : ((const float*)B)[j];
}

// ---------- fused QKV LDS GEMM: z in {0,1,2} selects (X, Wt, bias, Y) by OFFSET ----
// Tile 64(M)x128(N), BK=64; 4 waves 2x2, wave tile 32x64. All pointer roles are
// single non-aliased bases (round-3 aliased-restrict landmine structurally absent).
__global__ __launch_bounds__(256) void gemm_qkv(
    const void* __restrict__ X0, const void* __restrict__ X1, const void* __restrict__ X2,
    const ushort_t* __restrict__ WtBase, const float* __restrict__ biasBase,
    ushort_t* __restrict__ YBase, const int* __restrict__ flag) {
  const int isbf = flag[0];
  const int z = blockIdx.z;
  const void* X = (z == 0) ? X0 : (z == 1) ? X1 : X2;
  const ushort_t* Wt = WtBase + (size_t)z * HID * HID;
  const float* biasF = biasBase + (size_t)z * HID;
  ushort_t* Y = YBase + (size_t)z * MTOT * HID;

  const int tid = threadIdx.x;
  const int wid = tid >> 6, lane = tid & 63;
  const int id = lane & 15, quad = lane >> 4;
  const int wm = wid >> 1, wn = wid & 1;
  const int m0 = blockIdx.x * 64, n0 = blockIdx.y * 128;

  __shared__ ushort_t At[64 * 72];    // [m][k] stride 72
  __shared__ ushort_t Bt[128 * 72];   // [n][k] stride 72

  const int srow = tid >> 3;          // 0..31
  const int scol = (tid & 7) * 8;     // 0..56

  floatx4 acc[2][4];
#pragma unroll
  for (int i = 0; i < 2; ++i)
#pragma unroll
    for (int j = 0; j < 4; ++j) acc[i][j] = (floatx4){0.f, 0.f, 0.f, 0.f};

  for (int k0 = 0; k0 < HID; k0 += 64) {
    ushort8v aR[2], bR[4];
    if (isbf) {
      const ushort_t* ap = (const ushort_t*)X + (long)(m0 + srow) * HID + k0 + scol;
#pragma unroll
      for (int p = 0; p < 2; ++p) aR[p] = *(const ushort8v*)(ap + (long)p * 32 * HID);
    } else {
      const float* apf = (const float*)X + (long)(m0 + srow) * HID + k0 + scol;
#pragma unroll
      for (int p = 0; p < 2; ++p) {
        floatx4 f0 = *(const floatx4*)(apf + (long)p * 32 * HID);
        floatx4 f1 = *(const floatx4*)(apf + (long)p * 32 * HID + 4);
#pragma unroll
        for (int i = 0; i < 4; ++i) { aR[p][i] = f2bf(f0[i]); aR[p][4 + i] = f2bf(f1[i]); }
      }
    }
    {
      const ushort_t* bp = Wt + (long)(n0 + srow) * HID + k0 + scol;
#pragma unroll
      for (int p = 0; p < 4; ++p) bR[p] = *(const ushort8v*)(bp + (long)p * 32 * HID);
    }
    __syncthreads();   // previous iter's LDS reads complete
#pragma unroll
    for (int p = 0; p < 2; ++p) *(ushort8v*)(&At[(srow + 32 * p) * 72 + scol]) = aR[p];
#pragma unroll
    for (int p = 0; p < 4; ++p) *(ushort8v*)(&Bt[(srow + 32 * p) * 72 + scol]) = bR[p];
    __syncthreads();
#pragma unroll
    for (int kk = 0; kk < 64; kk += 32) {
      ushort8v af[2], bf4[4];
#pragma unroll
      for (int ms = 0; ms < 2; ++ms) af[ms] = *(const ushort8v*)(&At[(wm * 32 + ms * 16 + id) * 72 + kk + quad * 8]);
#pragma unroll
      for (int ns = 0; ns < 4; ++ns) bf4[ns] = *(const ushort8v*)(&Bt[(wn * 64 + ns * 16 + id) * 72 + kk + quad * 8]);
#pragma unroll
      for (int ms = 0; ms < 2; ++ms)
#pragma unroll
        for (int ns = 0; ns < 4; ++ns)
          acc[ms][ns] = __builtin_amdgcn_mfma_f32_16x16x32_bf16(asbf(af[ms]), asbf(bf4[ns]), acc[ms][ns], 0, 0, 0);
    }
  }
#pragma unroll
  for (int ns = 0; ns < 4; ++ns) {
    float bv = biasF[n0 + wn * 64 + ns * 16 + id];
    int col = n0 + wn * 64 + ns * 16 + id;
#pragma unroll
    for (int ms = 0; ms < 2; ++ms) {
      int row0 = m0 + wm * 32 + ms * 16 + quad * 4;
#pragma unroll
      for (int r = 0; r < 4; ++r)
        Y[(long)(row0 + r) * HID + col] = f2bf(acc[ms][ns][r] + bv);
    }
  }
}

// ---------- LDS-staged GEMM (output proj, round-9 proven verbatim) ----------
__global__ __launch_bounds__(256) void gemm_lds_out(
    const ushort_t* __restrict__ X, const ushort_t* __restrict__ Wt,
    const float* __restrict__ biasF, void* __restrict__ out,
    const int* __restrict__ flag) {
  const int isbf = flag[0];
  const int tid = threadIdx.x;
  const int wid = tid >> 6, lane = tid & 63;
  const int id = lane & 15, quad = lane >> 4;
  const int wm = wid >> 1, wn = wid & 1;
  const int m0 = blockIdx.x * 64, n0 = blockIdx.y * 128;

  __shared__ ushort_t At[64 * 72];
  __shared__ ushort_t Bt[128 * 72];

  const int srow = tid >> 3;
  const int scol = (tid & 7) * 8;

  floatx4 acc[2][4];
#pragma unroll
  for (int i = 0; i < 2; ++i)
#pragma unroll
    for (int j = 0; j < 4; ++j) acc[i][j] = (floatx4){0.f, 0.f, 0.f, 0.f};

  for (int k0 = 0; k0 < HID; k0 += 64) {
    ushort8v aR[2], bR[4];
    {
      const ushort_t* ap = X + (long)(m0 + srow) * HID + k0 + scol;
#pragma unroll
      for (int p = 0; p < 2; ++p) aR[p] = *(const ushort8v*)(ap + (long)p * 32 * HID);
      const ushort_t* bp = Wt + (long)(n0 + srow) * HID + k0 + scol;
#pragma unroll
      for (int p = 0; p < 4; ++p) bR[p] = *(const ushort8v*)(bp + (long)p * 32 * HID);
    }
    __syncthreads();
#pragma unroll
    for (int p = 0; p < 2; ++p) *(ushort8v*)(&At[(srow + 32 * p) * 72 + scol]) = aR[p];
#pragma unroll
    for (int p = 0; p < 4; ++p) *(ushort8v*)(&Bt[(srow + 32 * p) * 72 + scol]) = bR[p];
    __syncthreads();
#pragma unroll
    for (int kk = 0; kk < 64; kk += 32) {
      ushort8v af[2], bf4[4];
#pragma unroll
      for (int ms = 0; ms < 2; ++ms) af[ms] = *(const ushort8v*)(&At[(wm * 32 + ms * 16 + id) * 72 + kk + quad * 8]);
#pragma unroll
      for (int ns = 0; ns < 4; ++ns) bf4[ns] = *(const ushort8v*)(&Bt[(wn * 64 + ns * 16 + id) * 72 + kk + quad * 8]);
#pragma unroll
      for (int ms = 0; ms < 2; ++ms)
#pragma unroll
        for (int ns = 0; ns < 4; ++ns)
          acc[ms][ns] = __builtin_amdgcn_mfma_f32_16x16x32_bf16(asbf(af[ms]), asbf(bf4[ns]), acc[ms][ns], 0, 0, 0);
    }
  }
#pragma unroll
  for (int ns = 0; ns < 4; ++ns) {
    float bv = biasF[n0 + wn * 64 + ns * 16 + id];
    int col = n0 + wn * 64 + ns * 16 + id;
#pragma unroll
    for (int ms = 0; ms < 2; ++ms) {
      int row0 = m0 + wm * 32 + ms * 16 + quad * 4;
      if (isbf) {
        ushort_t* o = (ushort_t*)out;
#pragma unroll
        for (int r = 0; r < 4; ++r) o[(long)(row0 + r) * HID + col] = f2bf(acc[ms][ns][r] + bv);
      } else {
        float* o = (float*)out;
#pragma unroll
        for (int r = 0; r < 4; ++r) o[(long)(row0 + r) * HID + col] = acc[ms][ns][r] + bv;
      }
    }
  }
}

// ---------- flash attention — S^T, V staged via packed dword writes ----------
// V-transpose: thread loads 2 adjacent key rows, packs (V[2k+1][d]<<16)|V[2k][d],
// 8 conflict-free ds_write_b32 (32 lanes -> 32 banks, 2-way across halves = free).
// Replaces 16 conflicted b16 stores + 16 movs. Bit-exact data movement.
__global__ __launch_bounds__(256) void flash_attn(
    const ushort_t* __restrict__ Q, const ushort_t* __restrict__ K,
    const ushort_t* __restrict__ V, const int* __restrict__ mask,
    ushort_t* __restrict__ ctx) {
  const int qblk = blockIdx.x, h = blockIdx.y, b = blockIdx.z;
  const int tid = threadIdx.x;
  const int wid = tid >> 6, lane = tid & 63;
  const int id = lane & 15, quad = lane >> 4;

  __shared__ ushort_t Kt[64 * 72];       // [key][d] stride 72
  __shared__ ushort_t Vt[64 * 72];       // [d][key] stride 72 (transposed)
  __shared__ ushort_t Pl[4][32 * 72];    // per-wave P as [q][key] stride 72

  const ushort_t* Qb = Q + (long)(b * SEQ + qblk * 128 + wid * 32) * HID + h * HD;
  const ushort_t* Kb = K + (long)(b * SEQ) * HID + h * HD;
  const ushort_t* Vb = V + (long)(b * SEQ) * HID + h * HD;
  const int* mrow = mask + b * SEQ;

  ushort8v qf[2][2];
#pragma unroll
  for (int qs = 0; qs < 2; ++qs)
#pragma unroll
    for (int kh = 0; kh < 2; ++kh)
      qf[qs][kh] = *(const ushort8v*)(Qb + (qs * 16 + id) * HID + kh * 32 + quad * 8);

  floatx4 o[4][2];
  float m_i[2] = {-1e30f, -1e30f}, l_i[2] = {0.f, 0.f};
#pragma unroll
  for (int dg = 0; dg < 4; ++dg) { o[dg][0] = (floatx4){0,0,0,0}; o[dg][1] = (floatx4){0,0,0,0}; }

  const int skey = tid >> 2;             // K staging: 0..63
  const int sdc  = (tid & 3) * 16;       // K staging: 0,16,32,48
  const int vkp  = (tid & 31) * 2;       // V staging: key pair 0..62
  const int vdc  = (tid >> 5) * 8;       // V staging: d col 0..56

  for (int kb = 0; kb < SEQ / 64; ++kb) {
    // ---- stage K row-major (b128), V transposed via packed dwords ----
    {
      const ushort_t* kpp = Kb + (long)(kb * 64 + skey) * HID + sdc;
      ushort8v k0v = *(const ushort8v*)(kpp);
      ushort8v k1v = *(const ushort8v*)(kpp + 8);
      *(ushort8v*)(&Kt[skey * 72 + sdc])     = k0v;
      *(ushort8v*)(&Kt[skey * 72 + sdc + 8]) = k1v;
      const ushort_t* vp0 = Vb + (long)(kb * 64 + vkp) * HID + vdc;
      ushort8v v0v = *(const ushort8v*)(vp0);
      ushort8v v1v = *(const ushort8v*)(vp0 + HID);
#pragma unroll
      for (int i = 0; i < 8; ++i) {
        unsigned int dw = (unsigned int)v0v[i] | ((unsigned int)v1v[i] << 16);
        *(unsigned int*)(&Vt[(vdc + i) * 72 + vkp]) = dw;
      }
    }
    __syncthreads();

    floatx4 st[2][4];
#pragma unroll
    for (int ks = 0; ks < 4; ++ks) {
      ushort8v kf0 = *(const ushort8v*)(&Kt[(ks * 16 + id) * 72 + quad * 8]);
      ushort8v kf1 = *(const ushort8v*)(&Kt[(ks * 16 + id) * 72 + 32 + quad * 8]);
#pragma unroll
      for (int qs = 0; qs < 2; ++qs) {
        floatx4 a = (floatx4){0,0,0,0};
        a = __builtin_amdgcn_mfma_f32_16x16x32_bf16(asbf(kf0), asbf(qf[qs][0]), a, 0, 0, 0);
        a = __builtin_amdgcn_mfma_f32_16x16x32_bf16(asbf(kf1), asbf(qf[qs][1]), a, 0, 0, 0);
        st[qs][ks] = a;
      }
    }
#pragma unroll
    for (int ks = 0; ks < 4; ++ks) {
      intx4 mv = *(const intx4*)(mrow + kb * 64 + ks * 16 + quad * 4);
#pragma unroll
      for (int r = 0; r < 4; ++r) {
        float s0 = st[0][ks][r] * 0.125f, s1 = st[1][ks][r] * 0.125f;
        st[0][ks][r] = mv[r] ? s0 : -1e9f;
        st[1][ks][r] = mv[r] ? s1 : -1e9f;
      }
    }
#pragma unroll
    for (int qs = 0; qs < 2; ++qs) {
      float mx = st[qs][0][0];
#pragma unroll
      for (int ks = 0; ks < 4; ++ks)
#pragma unroll
        for (int r = 0; r < 4; ++r) mx = fmaxf(mx, st[qs][ks][r]);
      mx = fmaxf(mx, __shfl_xor(mx, 16));
      mx = fmaxf(mx, __shfl_xor(mx, 32));
      float mnew = fmaxf(m_i[qs], mx);
      float alpha = __expf(m_i[qs] - mnew);
      float rs = 0.f;
#pragma unroll
      for (int ks = 0; ks < 4; ++ks) {
        ushort4v pk;
#pragma unroll
        for (int r = 0; r < 4; ++r) {
          float p = __expf(st[qs][ks][r] - mnew);
          rs += p;
          pk[r] = f2bf(p);
        }
        *(ushort4v*)(&Pl[wid][(qs * 16 + id) * 72 + ks * 16 + quad * 4]) = pk;
      }
      rs += __shfl_xor(rs, 16);
      rs += __shfl_xor(rs, 32);
      l_i[qs] = l_i[qs] * alpha + rs;
      m_i[qs] = mnew;
#pragma unroll
      for (int dg = 0; dg < 4; ++dg) o[dg][qs] *= alpha;
    }
    __syncthreads();   // P visible before PV reads

#pragma unroll
    for (int kc = 0; kc < 2; ++kc) {
      ushort8v pf0 = *(const ushort8v*)(&Pl[wid][(0 * 16 + id) * 72 + kc * 32 + quad * 8]);
      ushort8v pf1 = *(const ushort8v*)(&Pl[wid][(1 * 16 + id) * 72 + kc * 32 + quad * 8]);
#pragma unroll
      for (int dg = 0; dg < 4; ++dg) {
        ushort8v vf = *(const ushort8v*)(&Vt[(dg * 16 + id) * 72 + kc * 32 + quad * 8]);
        o[dg][0] = __builtin_amdgcn_mfma_f32_16x16x32_bf16(asbf(vf), asbf(pf0), o[dg][0], 0, 0, 0);
        o[dg][1] = __builtin_amdgcn_mfma_f32_16x16x32_bf16(asbf(vf), asbf(pf1), o[dg][1], 0, 0, 0);
      }
    }
    __syncthreads();
  }

#pragma unroll
  for (int qs = 0; qs < 2; ++qs) {
    float inv = 1.0f / l_i[qs];
    long qrow = (long)(b * SEQ + qblk * 128 + wid * 32 + qs * 16 + id);
#pragma unroll
    for (int dg = 0; dg < 4; ++dg) {
      ushort4v pk;
#pragma unroll
      for (int r = 0; r < 4; ++r) pk[r] = f2bf(o[dg][qs][r] * inv);
      *(ushort4v*)(&ctx[qrow * HID + h * HD + dg * 16 + quad * 4]) = pk;
    }
  }
}

extern "C" void kernel_launch(void* const* d_in, const int* in_sizes, int n_in,
                              void* d_out, int out_size, void* d_ws, size_t ws_size,
                              hipStream_t stream) {
  const void* values = d_in[0];
  const void* keys   = d_in[1];
  const void* query  = d_in[2];
  const int*  mask   = (const int*)d_in[3];
  const void* Wq = d_in[4];  const void* bq = d_in[5];
  const void* Wk = d_in[6];  const void* bk = d_in[7];
  const void* Wv = d_in[8];  const void* bv = d_in[9];
  const void* Wo = d_in[10]; const void* bo = d_in[11];

  ushort_t* ws = (ushort_t*)d_ws;
  const size_t NEL = (size_t)MTOT * HID;
  ushort_t* Qp  = ws;                       // Qp/Kp/Vp contiguous (gemm_qkv offsets)
  ushort_t* Kp  = ws + NEL;
  ushort_t* Vp  = ws + 2 * NEL;
  ushort_t* Cp  = ws + 3 * NEL;
  ushort_t* WqT = ws + 4 * NEL;             // WqT/WkT/WvT contiguous
  ushort_t* WkT = WqT + (size_t)HID * HID;
  ushort_t* WvT = WkT + (size_t)HID * HID;
  ushort_t* WoT = WvT + (size_t)HID * HID;
  float* biasF  = (float*)(WoT + (size_t)HID * HID);   // q,k,v,o contiguous
  int* flag     = (int*)(biasF + 4 * HID);

  detect_dtype<<<1, 64, 0, stream>>>((const unsigned int*)query, flag);
  prep_w<<<dim3(1024, 4), 256, 0, stream>>>(Wq, Wk, Wv, Wo, WqT, WkT, WvT, WoT, flag);
  prep_b<<<8, 256, 0, stream>>>(bq, bk, bv, bo, biasF, flag);

  // fused QKV: grid (128, 4, 3) = 1536 blocks (~5 blocks/CU, LDS-capped)
  gemm_qkv<<<dim3(MTOT / 64, HID / 128, 3), 256, 0, stream>>>(
      query, keys, values, WqT, biasF, Qp, flag);

  flash_attn<<<dim3(SEQ / 128, NH, BATCH), 256, 0, stream>>>(Qp, Kp, Vp, mask, Cp);

  gemm_lds_out<<<dim3(MTOT / 64, HID / 128), 256, 0, stream>>>(
      Cp, WoT, biasF + 3 * HID, d_out, flag);
}